// Round 10
// baseline (409.459 us; speedup 1.0000x reference)
//
#include <hip/hip_runtime.h>
#include <hip/hip_bf16.h>

typedef __bf16 bf16_t;
typedef __bf16 bf16x8 __attribute__((ext_vector_type(8)));
typedef __bf16 bf16x4 __attribute__((ext_vector_type(4)));
typedef float f32x4 __attribute__((ext_vector_type(4)));

#define B_DIM 4
#define NQ 2048
#define NK 2048
#define DMODEL 1024
#define NH 8
#define DHEAD 128

#define AS1 __attribute__((address_space(1)))
#define AS3 __attribute__((address_space(3)))

__device__ __forceinline__ void gl_lds16(const void* g, void* l) {
    __builtin_amdgcn_global_load_lds((const AS1 void*)g, (AS3 void*)l, 16, 0, 0);
}

// ---------------------------------------------------------------------------
// fp32 -> bf16 conversion, 6 pairs selected by blockIdx.y
// ---------------------------------------------------------------------------
struct CvtArgs {
    const float* s[6];
    bf16_t* d[6];
    int n[6];
};

__global__ __launch_bounds__(256) void cvt_k(CvtArgs a) {
    const int p = blockIdx.y;
    const float* s = a.s[p];
    bf16_t* d = a.d[p];
    const int n = a.n[p];
    const int stride = gridDim.x * 256 * 8;
    for (int i = (blockIdx.x * 256 + threadIdx.x) * 8; i < n; i += stride) {
        float4 x0 = *(const float4*)(s + i);
        float4 x1 = *(const float4*)(s + i + 4);
        bf16x8 o = {(bf16_t)x0.x, (bf16_t)x0.y, (bf16_t)x0.z, (bf16_t)x0.w,
                    (bf16_t)x1.x, (bf16_t)x1.y, (bf16_t)x1.z, (bf16_t)x1.w};
        *(bf16x8*)(d + i) = o;
    }
}

// ---------------------------------------------------------------------------
// Fused Q/K/V projection: z = blockIdx.z selects (A, W, bias, epilogue).
// C[M,N] = A[M,1024] * W[N,1024]^T + bias.
// z==2 scatters to vT8 in fp8 e4m3 (PV path runs fp8 -- R10).
// ---------------------------------------------------------------------------
__global__ __launch_bounds__(256) void proj_k(
    const bf16_t* Qc, const bf16_t* Kc,
    const bf16_t* Wqc, const bf16_t* Wkc, const bf16_t* Wvc,
    const float* bq, const float* bk, const float* bv,
    bf16_t* qbb, bf16_t* kbb, unsigned char* vT8)
{
    const int K = DMODEL, N = DMODEL;
    const int z = blockIdx.z;
    const bf16_t* A  = (z == 0) ? Qc : Kc;
    const bf16_t* Bw = (z == 0) ? Wqc : (z == 1) ? Wkc : Wvc;
    const float* bias = (z == 0) ? bq : (z == 1) ? bk : bv;
    bf16_t* Cb = (z == 0) ? qbb : kbb;

    const int tid  = threadIdx.x;
    const int lane = tid & 63;
    const int wv   = tid >> 6;
    const int l16  = lane & 15;
    const int quad = (lane >> 4) & 3;
    const int kc4  = lane >> 4;
    const int wr   = wv >> 1, wc = wv & 1;
    const int rowBase = blockIdx.y * 128;
    const int colBase = blockIdx.x * 128;

    __shared__ bf16_t sA[4096];
    __shared__ bf16_t sB[4096];

    const bf16_t* gA = A + (size_t)(rowBase + wv * 32 + l16) * K + kc4 * 8;
    const bf16_t* gB = Bw + (size_t)(colBase + wv * 32 + l16) * K + kc4 * 8;
    bf16_t* lA0 = &sA[(wv * 2) * 512];
    bf16_t* lA1 = &sA[(wv * 2 + 1) * 512];
    bf16_t* lB0 = &sB[(wv * 2) * 512];
    bf16_t* lB1 = &sB[(wv * 2 + 1) * 512];

    const f32x4 fz = {0.f, 0.f, 0.f, 0.f};
    f32x4 acc[4][4];
#pragma unroll
    for (int i = 0; i < 4; i++)
#pragma unroll
        for (int j = 0; j < 4; j++) acc[i][j] = fz;

    for (int k0 = 0; k0 < K; k0 += 32) {
        gl_lds16(gA, lA0);
        gl_lds16(gA + (size_t)16 * K, lA1);
        gl_lds16(gB, lB0);
        gl_lds16(gB + (size_t)16 * K, lB1);
        gA += 32; gB += 32;
        __syncthreads();

        bf16x8 aF[4], bF[4];
#pragma unroll
        for (int mi = 0; mi < 4; mi++)
            aF[mi] = *(const bf16x8*)(&sA[(wr * 4 + mi) * 512 + (quad * 16 + l16) * 8]);
#pragma unroll
        for (int ni = 0; ni < 4; ni++)
            bF[ni] = *(const bf16x8*)(&sB[(wc * 4 + ni) * 512 + (quad * 16 + l16) * 8]);
#pragma unroll
        for (int mi = 0; mi < 4; mi++)
#pragma unroll
            for (int ni = 0; ni < 4; ni++)
                acc[mi][ni] = __builtin_amdgcn_mfma_f32_16x16x32_bf16(
                    aF[mi], bF[ni], acc[mi][ni], 0, 0, 0);
        __syncthreads();
    }

#pragma unroll
    for (int mi = 0; mi < 4; mi++) {
#pragma unroll
        for (int ni = 0; ni < 4; ni++) {
            int row0 = rowBase + wr * 64 + mi * 16 + quad * 4;
            int col  = colBase + wc * 64 + ni * 16 + l16;
            float bvv = bias[col];
            if (z != 2) {
#pragma unroll
                for (int r = 0; r < 4; r++)
                    Cb[(size_t)(row0 + r) * N + col] = (bf16_t)(acc[mi][ni][r] + bvv);
            } else {
                int b  = row0 >> 11;
                int n0 = row0 & 2047;     // key index (multiple of 4)
                int hh = col >> 7;
                int dd = col & 127;
                int d0 = __builtin_amdgcn_cvt_pk_fp8_f32(
                    acc[mi][ni][0] + bvv, acc[mi][ni][1] + bvv, 0, false);
                d0 = __builtin_amdgcn_cvt_pk_fp8_f32(
                    acc[mi][ni][2] + bvv, acc[mi][ni][3] + bvv, d0, true);
                *(int*)(vT8 + (size_t)((b * NH + hh) * DHEAD + dd) * NK + n0) = d0;
            }
        }
    }
}

// ---------------------------------------------------------------------------
// Wo GEMM (MODE1): Cf = resid + relu(acc + bias).  resid is bf16 LN output.
// ---------------------------------------------------------------------------
__global__ __launch_bounds__(256) void gemm_wo(
    const bf16_t* __restrict__ A, const bf16_t* __restrict__ Bw,
    const float* __restrict__ bias, const bf16_t* resid, float* Cf,
    int M, int N, int K)
{
    const int tid  = threadIdx.x;
    const int lane = tid & 63;
    const int wv   = tid >> 6;
    const int l16  = lane & 15;
    const int quad = (lane >> 4) & 3;
    const int kc4  = lane >> 4;
    const int wr   = wv >> 1, wc = wv & 1;
    const int rowBase = blockIdx.y * 128;
    const int colBase = blockIdx.x * 128;

    __shared__ bf16_t sA[4096];
    __shared__ bf16_t sB[4096];

    const bf16_t* gA = A + (size_t)(rowBase + wv * 32 + l16) * K + kc4 * 8;
    const bf16_t* gB = Bw + (size_t)(colBase + wv * 32 + l16) * K + kc4 * 8;
    bf16_t* lA0 = &sA[(wv * 2) * 512];
    bf16_t* lA1 = &sA[(wv * 2 + 1) * 512];
    bf16_t* lB0 = &sB[(wv * 2) * 512];
    bf16_t* lB1 = &sB[(wv * 2 + 1) * 512];

    const f32x4 fz = {0.f, 0.f, 0.f, 0.f};
    f32x4 acc[4][4];
#pragma unroll
    for (int i = 0; i < 4; i++)
#pragma unroll
        for (int j = 0; j < 4; j++) acc[i][j] = fz;

    for (int k0 = 0; k0 < K; k0 += 32) {
        gl_lds16(gA, lA0);
        gl_lds16(gA + (size_t)16 * K, lA1);
        gl_lds16(gB, lB0);
        gl_lds16(gB + (size_t)16 * K, lB1);
        gA += 32; gB += 32;
        __syncthreads();

        bf16x8 aF[4], bF[4];
#pragma unroll
        for (int mi = 0; mi < 4; mi++)
            aF[mi] = *(const bf16x8*)(&sA[(wr * 4 + mi) * 512 + (quad * 16 + l16) * 8]);
#pragma unroll
        for (int ni = 0; ni < 4; ni++)
            bF[ni] = *(const bf16x8*)(&sB[(wc * 4 + ni) * 512 + (quad * 16 + l16) * 8]);
#pragma unroll
        for (int mi = 0; mi < 4; mi++)
#pragma unroll
            for (int ni = 0; ni < 4; ni++)
                acc[mi][ni] = __builtin_amdgcn_mfma_f32_16x16x32_bf16(
                    aF[mi], bF[ni], acc[mi][ni], 0, 0, 0);
        __syncthreads();
    }

#pragma unroll
    for (int mi = 0; mi < 4; mi++) {
#pragma unroll
        for (int ni = 0; ni < 4; ni++) {
            int row0 = rowBase + wr * 64 + mi * 16 + quad * 4;
            int col  = colBase + wc * 64 + ni * 16 + l16;
            float bvv = bias[col];
#pragma unroll
            for (int r = 0; r < 4; r++) {
                float v = acc[mi][ni][r] + bvv;
                v = v > 0.f ? v : 0.f;
                Cf[(size_t)(row0 + r) * N + col] =
                    (float)resid[(size_t)(row0 + r) * N + col] + v;
            }
        }
    }
}

// ---------------------------------------------------------------------------
// Transposed flash attention: S^T = K Q^T (bf16), O^T = V^T P^T (fp8 e4m3).
// v10 = v9 + fp8 PV path:
//  - V staged in LDS as fp8 (8 KB/tile, was 16): d-row-major 64 B rows,
//    XOR swizzle (l16&3)<<4 pre-applied on the GLOBAL source (gl_lds16 dest
//    must stay linear), matching XOR on the read -> ~4-way banks on b64.
//  - P packed to fp8: 4 keys/dword -> 8 shuffles per iter (was 16).
//  - PV via mfma_f32_16x16x32_fp8_fp8 (same shape/rate as bf16).
// K/Q stay bf16 (exp-amplified logit path keeps precision).
// LDS read/CU: 16.8 -> 12.6 MB.  8 waves x 16 q-rows, 4 waves/SIMD.
// ---------------------------------------------------------------------------
__global__ __launch_bounds__(512, 4) void attn_k(
    const bf16_t* __restrict__ qb, const bf16_t* __restrict__ kb,
    const unsigned char* __restrict__ vT8, bf16_t* __restrict__ O)
{
    const int tid  = threadIdx.x;
    const int lane = tid & 63;
    const int wv   = tid >> 6;      // 0..7
    const int l16  = lane & 15;
    const int quad = (lane >> 4) & 3;
    const int bh   = blockIdx.x;    // bh-major: same bh -> same XCD
    const int b    = bh >> 3;
    const int h    = bh & 7;
    const int qt   = blockIdx.y * 128;
    const int qrow = b * NQ + qt + wv * 16;   // 16 q-rows per wave
    const int NKT  = NK / 64;       // 32 key-tiles

    __shared__ bf16_t sK[2][8192];          // dbuf: 16 KB/tile (64 keys x 128 d bf16)
    __shared__ unsigned char sV8[2][8192];  // dbuf: 8 KB/tile (128 d x 64 k fp8)

    const bf16_t* gKb = kb + ((size_t)b * NK + l16) * DMODEL + h * DHEAD + quad * 8;

    // K: 16 frags/tile, 8 waves -> 2 gl_lds16 each.
    // V: 8 KB/tile, 8 waves -> 1 gl_lds16 each (wave wv = d-rows [16wv,16wv+16)).
    //   lane l: row=l>>2, kseg=l&3, source k-block kseg^(row&3) (write-side swizzle).
    auto stage = [&](int tt, int bufi) {
        const int kt = tt * 64;
#pragma unroll
        for (int j = 0; j < 2; j++) {
            const int f = wv * 2 + j;
            const int kbi = f >> 2, c = f & 3;
            gl_lds16(gKb + (size_t)(kt + kbi * 16) * DMODEL + c * 32,
                     &sK[bufi][f * 512]);
        }
        const int row = lane >> 2;
        const int ksw = (lane & 3) ^ (row & 3);
        gl_lds16(vT8 + (size_t)(bh * DHEAD + wv * 16 + row) * NK + kt + ksw * 16,
                 &sV8[bufi][wv * 1024]);
    };

    stage(0, 0);   // prologue prefetch overlaps the Q-fragment loads below

    // Q as B-operand fragments: q = qrow + l16, d = c*32 + quad*8
    bf16x8 qF[4];
#pragma unroll
    for (int c = 0; c < 4; c++)
        qF[c] = *(const bf16x8*)(qb + (size_t)(qrow + l16) * DMODEL +
                                 h * DHEAD + c * 32 + quad * 8);

    const f32x4 fz = {0.f, 0.f, 0.f, 0.f};
    f32x4 accO[8];                // O^T frags per d-block
#pragma unroll
    for (int db = 0; db < 8; db++) accO[db] = fz;
    float mq = -3e38f;
    float lq = 0.f;
    const float SC2 = 0.08838834764831845f * 1.44269504089f;  // log2(e)/sqrt(128)

    const int qa   = (quad & 1) * 2;
    const int srcA = l16 + 16 * qa;
    const int srcB = srcA + 16;
    const bool hi  = (quad >> 1) != 0;
    const int vxor = (l16 & 3) << 4;      // read-side V swizzle

    __syncthreads();              // tile 0 staged (vmcnt drained)
    int cur = 0;

    for (int t = 0; t < NKT; t++) {
        // ---- prefetch next tile into the alternate buffer (no wait here)
        if (t + 1 < NKT) stage(t + 1, cur ^ 1);

        // ---- S^T = K Q^T : A = K frags (bf16), B = Q frag
        f32x4 S[4];
        __builtin_amdgcn_s_setprio(1);
#pragma unroll
        for (int kb4 = 0; kb4 < 4; kb4++) {
            S[kb4] = fz;
#pragma unroll
            for (int c = 0; c < 4; c++) {
                bf16x8 kF = *(const bf16x8*)(&sK[cur][(kb4 * 4 + c) * 512 + lane * 8]);
                S[kb4] = __builtin_amdgcn_mfma_f32_16x16x32_bf16(kF, qF[c], S[kb4], 0, 0, 0);
            }
        }
        __builtin_amdgcn_s_setprio(0);

        // ---- online softmax: lane-local defer-max gate (no shfl common path)
        float mxl = fmaxf(fmaxf(fmaxf(S[0][0], S[0][1]), fmaxf(S[0][2], S[0][3])),
                    fmaxf(fmaxf(S[1][0], S[1][1]), fmaxf(S[1][2], S[1][3])));
        mxl = fmaxf(mxl, fmaxf(fmaxf(fmaxf(S[2][0], S[2][1]), fmaxf(S[2][2], S[2][3])),
                          fmaxf(fmaxf(S[3][0], S[3][1]), fmaxf(S[3][2], S[3][3]))));
        const bool need = !__all((mxl - mq) * SC2 <= 8.f);
        float al = 1.f;
        if (need) {    // rare: full cross-lane reduce + rescale
            float mx = fmaxf(mxl, __shfl_xor(mxl, 16));
            mx = fmaxf(mx, __shfl_xor(mx, 32));
            float mn = fmaxf(mq, mx);
            al = exp2f((mq - mn) * SC2);
            mq = mn;
        }
        const float mc = mq * SC2;
        float sum = 0.f;
#pragma unroll
        for (int kb4 = 0; kb4 < 4; kb4++)
#pragma unroll
            for (int r = 0; r < 4; r++) {
                float p = exp2f(fmaf(S[kb4][r], SC2, -mc));
                S[kb4][r] = p;
                sum += p;
            }
        lq = lq * al + sum;       // lane-local partial (this lane's 16 keys)
        if (need) {
#pragma unroll
            for (int db = 0; db < 8; db++)
#pragma unroll
                for (int r = 0; r < 4; r++) accO[db][r] *= al;
        }

        // ---- P -> fp8: 4 keys/dword; 8 shuffles build B-operand frags
        int pk8[4];
#pragma unroll
        for (int kb4 = 0; kb4 < 4; kb4++) {
            int d0 = __builtin_amdgcn_cvt_pk_fp8_f32(S[kb4][0], S[kb4][1], 0, false);
            pk8[kb4] = __builtin_amdgcn_cvt_pk_fp8_f32(S[kb4][2], S[kb4][3], d0, true);
        }
        long pF8[2];
#pragma unroll
        for (int kc = 0; kc < 2; kc++) {
            unsigned x0 = (unsigned)__shfl(pk8[2 * kc],     srcA);
            unsigned x1 = (unsigned)__shfl(pk8[2 * kc + 1], srcA);
            unsigned y0 = (unsigned)__shfl(pk8[2 * kc],     srcB);
            unsigned y1 = (unsigned)__shfl(pk8[2 * kc + 1], srcB);
            uint2 w = {hi ? x1 : x0, hi ? y1 : y0};
            pF8[kc] = __builtin_bit_cast(long, w);
        }

        // ---- O^T += V^T P^T : fp8 x fp8 MFMA, V from swizzled LDS (b64)
        __builtin_amdgcn_s_setprio(1);
#pragma unroll
        for (int kc = 0; kc < 2; kc++)
#pragma unroll
            for (int db = 0; db < 8; db++) {
                long vF8 = *(const long*)(&sV8[cur][db * 1024 + l16 * 64 +
                                                   ((kc * 32 + quad * 8) ^ vxor)]);
                accO[db] = __builtin_amdgcn_mfma_f32_16x16x32_fp8_fp8(
                    vF8, pF8[kc], accO[db], 0, 0, 0);
            }
        __builtin_amdgcn_s_setprio(0);

        // single barrier per iter: drains the prefetch + releases buffers
        __syncthreads();
        cur ^= 1;
    }

    // finalize denominator (cross-quad partials)
    float s = lq;
    s += __shfl_xor(s, 16);
    s += __shfl_xor(s, 32);
    const float inv = 1.0f / s;

    // O = acc/l + q residual (bf16 out); O^T frag: q=l16, d=db*16+quad*4+r
    const int grow = qrow + l16;
#pragma unroll
    for (int db = 0; db < 8; db++) {
        const int gcol = h * DHEAD + db * 16 + quad * 4;
        bf16x4 qr = *(const bf16x4*)(qb + (size_t)grow * DMODEL + gcol);
        bf16x4 o;
#pragma unroll
        for (int r = 0; r < 4; r++)
            o[r] = (bf16_t)(accO[db][r] * inv + (float)qr[r]);
        *(bf16x4*)(O + (size_t)grow * DMODEL + gcol) = o;
    }
}

// ---------------------------------------------------------------------------
// LayerNorm over rows of 1024, bf16 input -> bf16 output (post-attn LN)
// ---------------------------------------------------------------------------
__global__ __launch_bounds__(256) void lnb_k(
    const bf16_t* __restrict__ X, const float* __restrict__ g,
    const float* __restrict__ bta, bf16_t* __restrict__ Yb)
{
    const int row = blockIdx.x;
    const int t = threadIdx.x;
    bf16x4 xb = *(const bf16x4*)(X + (size_t)row * DMODEL + t * 4);
    float4 x = {(float)xb[0], (float)xb[1], (float)xb[2], (float)xb[3]};
    float s  = x.x + x.y + x.z + x.w;
    float sq = x.x * x.x + x.y * x.y + x.z * x.z + x.w * x.w;
#pragma unroll
    for (int o = 1; o < 64; o <<= 1) {
        s  += __shfl_xor(s, o);
        sq += __shfl_xor(sq, o);
    }
    __shared__ float ls[8];
    int w = t >> 6, ln = t & 63;
    if (ln == 0) { ls[w] = s; ls[4 + w] = sq; }
    __syncthreads();
    s  = ls[0] + ls[1] + ls[2] + ls[3];
    sq = ls[4] + ls[5] + ls[6] + ls[7];
    float mu  = s * (1.f / DMODEL);
    float var = sq * (1.f / DMODEL) - mu * mu;
    float rs  = rsqrtf(var + 1e-5f);
    float4 gv = *(const float4*)(g + t * 4);
    float4 bv = *(const float4*)(bta + t * 4);
    bf16x4 yb = {(bf16_t)((x.x - mu) * rs * gv.x + bv.x),
                 (bf16_t)((x.y - mu) * rs * gv.y + bv.y),
                 (bf16_t)((x.z - mu) * rs * gv.z + bv.z),
                 (bf16_t)((x.w - mu) * rs * gv.w + bv.w)};
    *(bf16x4*)(Yb + (size_t)row * DMODEL + t * 4) = yb;
}

// ---------------------------------------------------------------------------
// LayerNorm over rows of 1024, f32 input (final LN)
// ---------------------------------------------------------------------------
__global__ __launch_bounds__(256) void ln_k(
    const float* __restrict__ X, const float* __restrict__ g,
    const float* __restrict__ bta, float* __restrict__ Yf)
{
    const int row = blockIdx.x;
    const int t = threadIdx.x;
    float4 x = *(const float4*)(X + (size_t)row * DMODEL + t * 4);
    float s  = x.x + x.y + x.z + x.w;
    float sq = x.x * x.x + x.y * x.y + x.z * x.z + x.w * x.w;
#pragma unroll
    for (int o = 1; o < 64; o <<= 1) {
        s  += __shfl_xor(s, o);
        sq += __shfl_xor(sq, o);
    }
    __shared__ float ls[8];
    int w = t >> 6, ln = t & 63;
    if (ln == 0) { ls[w] = s; ls[4 + w] = sq; }
    __syncthreads();
    s  = ls[0] + ls[1] + ls[2] + ls[3];
    sq = ls[4] + ls[5] + ls[6] + ls[7];
    float mu  = s * (1.f / DMODEL);
    float var = sq * (1.f / DMODEL) - mu * mu;
    float rs  = rsqrtf(var + 1e-5f);
    float4 gv = *(const float4*)(g + t * 4);
    float4 bv = *(const float4*)(bta + t * 4);
    float4 y;
    y.x = (x.x - mu) * rs * gv.x + bv.x;
    y.y = (x.y - mu) * rs * gv.y + bv.y;
    y.z = (x.z - mu) * rs * gv.z + bv.z;
    y.w = (x.w - mu) * rs * gv.w + bv.w;
    *(float4*)(Yf + (size_t)row * DMODEL + t * 4) = y;
}

// ---------------------------------------------------------------------------
extern "C" void kernel_launch(void* const* d_in, const int* in_sizes, int n_in,
                              void* d_out, int out_size, void* d_ws, size_t ws_size,
                              hipStream_t stream)
{
    const float* Q  = (const float*)d_in[0];
    const float* Kx = (const float*)d_in[1];
    const float* Wq = (const float*)d_in[2];
    const float* bq = (const float*)d_in[3];
    const float* Wk = (const float*)d_in[4];
    const float* bk = (const float*)d_in[5];
    const float* Wv = (const float*)d_in[6];
    const float* bv = (const float*)d_in[7];
    const float* Wo = (const float*)d_in[8];
    const float* bo = (const float*)d_in[9];
    const float* g0 = (const float*)d_in[10];
    const float* b0 = (const float*)d_in[11];
    const float* g1 = (const float*)d_in[12];
    const float* b1 = (const float*)d_in[13];
    float* out = (float*)d_out;

    char* ws = (char*)d_ws;
    bf16_t* Qc  = (bf16_t*)(ws);                  // 16,777,216
    bf16_t* Kc  = (bf16_t*)(ws + 16777216);       // 16,777,216
    bf16_t* Wqc = (bf16_t*)(ws + 33554432);       // 2,097,152
    bf16_t* Wkc = (bf16_t*)(ws + 35651584);
    bf16_t* Wvc = (bf16_t*)(ws + 37748736);
    bf16_t* Woc = (bf16_t*)(ws + 39845888);
    bf16_t* qbb = (bf16_t*)(ws + 41943040);       // 16,777,216
    bf16_t* kbb = (bf16_t*)(ws + 58720256);       // 16,777,216
    unsigned char* vT8 = (unsigned char*)(ws + 75497472);  // 8,388,608 (fp8)
    bf16_t* Obuf = (bf16_t*)(ws + 92274688);      // 16,777,216 (bf16 attn out)
    float*  Lf  = (float*)(ws);                   // alias Qc+Kc (dead after proj)
    bf16_t* Lb  = kbb;                            // alias kbb (dead after attn)

    CvtArgs ca;
    ca.s[0] = Q;  ca.d[0] = Qc;  ca.n[0] = B_DIM * NQ * DMODEL;
    ca.s[1] = Kx; ca.d[1] = Kc;  ca.n[1] = B_DIM * NK * DMODEL;
    ca.s[2] = Wq; ca.d[2] = Wqc; ca.n[2] = DMODEL * DMODEL;
    ca.s[3] = Wk; ca.d[3] = Wkc; ca.n[3] = DMODEL * DMODEL;
    ca.s[4] = Wv; ca.d[4] = Wvc; ca.n[4] = DMODEL * DMODEL;
    ca.s[5] = Wo; ca.d[5] = Woc; ca.n[5] = DMODEL * DMODEL;
    cvt_k<<<dim3(512, 6), 256, 0, stream>>>(ca);

    const int M = B_DIM * NQ;  // 8192

    proj_k<<<dim3(DMODEL / 128, M / 128, 3), 256, 0, stream>>>(
        Qc, Kc, Wqc, Wkc, Wvc, bq, bk, bv, qbb, kbb, vT8);

    attn_k<<<dim3(B_DIM * NH, NQ / 128), 512, 0, stream>>>(qbb, kbb, vT8, Obuf);

    // ln0: bf16 in -> bf16 out (gemm_wo reads resid as bf16)
    lnb_k<<<dim3(M), 256, 0, stream>>>(Obuf, g0, b0, Lb);

    gemm_wo<<<dim3(DMODEL / 128, M / 128), 256, 0, stream>>>(
        Lb, Woc, bo, Lb, Lf, M, DMODEL, DMODEL);

    ln_k<<<dim3(M), 256, 0, stream>>>(Lf, g1, b1, out);
}